// Round 11
// baseline (41.558 us; speedup 1.0000x reference)
//
#include <hip/hip_runtime.h>
#include <hip/hip_fp16.h>

#define BS 64
#define LS 512
#define CL 32
#define WD 300
#define NC 100
#define CD 100
#define PD 100
#define NF 100
#define KK 3
#define OPAD 128                  // k-row padded to 128 f16 = 256 B = 8 full bank sweeps
#define PROW (KK*OPAD)            // 384 f16 = 768 B per char
#define PBYTES (NC*PROW*2)        // 76800 B
#define NV4 (PBYTES/16)           // 4800 uint4
#define OUTD 501
#define TPB 64                    // tokens per block
#define NTHR 1024

typedef _Float16 h2 __attribute__((ext_vector_type(2)));

// ---------- Kernel 1: P[c][k][o] = sum_i conv_w[o,i,k] * char_table[c,i] (f16) ----------
__global__ void precompute_P(const float* __restrict__ conv_w,
                             const float* __restrict__ char_table,
                             _Float16* __restrict__ P) {
    const int c = blockIdx.x;      // 0..99
    const int k = blockIdx.y;      // 0..2
    const int o = threadIdx.x;     // 0..127
    __shared__ float row[CD];
    if (o < CD) row[o] = char_table[c * CD + o];
    __syncthreads();
    float acc = 0.f;
    if (o < NF) {
        const float* w = conv_w + o * (CD * KK) + k;
        #pragma unroll 4
        for (int i = 0; i < CD; ++i) acc += w[i * KK] * row[i];
    }
    P[(c * KK + k) * OPAD + o] = (_Float16)acc;    // o in [100,128) stores 0
}

// ---------- Kernel 2: fused, wave-specialized, coalesced copies ----------
// Pre-barrier: all waves stage P->LDS, ballot privacy masks, pack char ids.
// Post-barrier: waves 0-7 = char CNN (LDS pipe), waves 8-15 = word/pos/dist
// (HBM pipe). Copy loops are scalar-coalesced on BOTH sides: consecutive
// lanes handle consecutive floats -> ~4-5 cache lines per wave store instead
// of 16-17 with the old 16B-stride scalar stores.
__global__ __launch_bounds__(NTHR, 8) void main_kernel(
        const int* __restrict__ input_word,
        const int* __restrict__ input_char,
        const int* __restrict__ input_pos,
        const float* __restrict__ word_table,
        const float* __restrict__ pos_table,
        const float* __restrict__ conv_b,
        const _Float16* __restrict__ Pg,
        float* __restrict__ out) {
    __shared__ alignas(16) _Float16 Pl[NC * PROW];         // 76800 B
    __shared__ alignas(16) unsigned char s_char[TPB * CL]; // 2048 B packed char ids
    __shared__ unsigned long long s_mask[LS / 64];         // 64 B  (total 78912 B -> 2 blocks/CU)

    const int tid  = threadIdx.x;
    const int tok0 = blockIdx.x * TPB;

    // ---- 1. P staging loads into regs (all waves) ----
    const uint4* src = (const uint4*)Pg;
    const uint4 s0 = src[tid];
    const uint4 s1 = src[tid + NTHR];
    const uint4 s2 = src[tid + 2 * NTHR];
    const uint4 s3 = src[tid + 3 * NTHR];
    uint4 s4 = {};
    const bool h4 = tid < (NV4 - 4 * NTHR);   // tid < 704 (wave-uniform boundary)
    if (h4) s4 = src[tid + 4 * NTHR];

    // ---- 2. privacy-mask ballot (threads 0..511) ----
    if (tid < LS) {
        const int p = input_pos[(tok0 >> 9) * LS + tid];
        const bool pm = (p == 3) | (p == 7) | (p == 11);
        const unsigned long long b = __ballot(pm);
        if ((tid & 63) == 0) s_mask[tid >> 6] = b;
    }

    // ---- 3. char ids packed to bytes (512 dwords) ----
    if (tid < (TPB * CL) / 4) {
        const int4 c4 = ((const int4*)(input_char + tok0 * CL))[tid];
        ((unsigned*)s_char)[tid] =
            (unsigned)c4.x | ((unsigned)c4.y << 8) | ((unsigned)c4.z << 16) | ((unsigned)c4.w << 24);
    }

    // ---- 4. write staged P to LDS, barrier ----
    {
        uint4* dst = (uint4*)Pl;
        dst[tid] = s0;
        dst[tid + NTHR] = s1;
        dst[tid + 2 * NTHR] = s2;
        dst[tid + 3 * NTHR] = s3;
        if (h4) dst[tid + 4 * NTHR] = s4;
    }
    __syncthreads();

    if (tid < 512) {
        // ================== CHAR ROLE: waves 0-7 ==================
        const int wid  = tid >> 6;
        const int lane = tid & 63;
        const int l    = lane & 15;          // filter octet (0..15)
        const char* Pb = (const char*)Pl + l * 16;
        const unsigned* s_cw = (const unsigned*)s_char;

        #pragma unroll 1
        for (int pass = 0; pass < 2; ++pass) {
            const int tb = wid * 8 + pass * 4 + (lane >> 4);   // token in block
            h2 a0[4], a1[4], m[4];
            #pragma unroll
            for (int i = 0; i < 4; ++i) {
                a0[i] = (h2)(_Float16)0;
                a1[i] = (h2)(_Float16)0;
                m[i]  = (h2)(_Float16)(-60000.f);
            }
            #pragma unroll 2
            for (int w = 0; w < CL / 4; ++w) {
                const unsigned wd = s_cw[tb * (CL / 4) + w];   // 4 packed char ids
                #pragma unroll
                for (int b = 0; b < 4; ++b) {
                    const int ca = (int)((wd >> (8 * b)) & 0xFFu) * (PROW * 2);
                    const uint4 r0 = *(const uint4*)(Pb + ca + 0 * (OPAD * 2));
                    const uint4 r1 = *(const uint4*)(Pb + ca + 1 * (OPAD * 2));
                    const uint4 r2 = *(const uint4*)(Pb + ca + 2 * (OPAD * 2));
                    #pragma unroll
                    for (int i = 0; i < 4; ++i) {
                        const unsigned c0 = (i == 0) ? r0.x : (i == 1) ? r0.y : (i == 2) ? r0.z : r0.w;
                        const unsigned c1 = (i == 0) ? r1.x : (i == 1) ? r1.y : (i == 2) ? r1.z : r1.w;
                        const unsigned c2 = (i == 0) ? r2.x : (i == 1) ? r2.y : (i == 2) ? r2.z : r2.w;
                        const h2 p0 = __builtin_bit_cast(h2, c0);
                        const h2 p1 = __builtin_bit_cast(h2, c1);
                        const h2 p2 = __builtin_bit_cast(h2, c2);
                        const h2 y = a0[i] + p2;               // y[t]
                        m[i]  = __builtin_elementwise_max(m[i], y);
                        a0[i] = a1[i] + p1;
                        a1[i] = p0;
                    }
                }
            }
            // tail: y[32] = a0, y[33] = a1; write cols 301..400
            if (l < 13) {
                float mm[8];
                #pragma unroll
                for (int i = 0; i < 4; ++i) {
                    const h2 v = __builtin_elementwise_max(m[i], __builtin_elementwise_max(a0[i], a1[i]));
                    mm[2 * i]     = (float)v.x;
                    mm[2 * i + 1] = (float)v.y;
                }
                const float4 b0 = *(const float4*)(conv_b + 8 * l);
                float* outc = out + (size_t)(tok0 + tb) * OUTD + 301 + 8 * l;
                outc[0] = tanhf(mm[0] + b0.x);
                outc[1] = tanhf(mm[1] + b0.y);
                outc[2] = tanhf(mm[2] + b0.z);
                outc[3] = tanhf(mm[3] + b0.w);
                if (l < 12) {
                    const float4 b1 = *(const float4*)(conv_b + 8 * l + 4);
                    outc[4] = tanhf(mm[4] + b1.x);
                    outc[5] = tanhf(mm[5] + b1.y);
                    outc[6] = tanhf(mm[6] + b1.z);
                    outc[7] = tanhf(mm[7] + b1.w);
                }
            }
        }
    } else {
        // ================== COPY ROLE: waves 8-15 ==================
        const int t2 = tid - 512;
        float* const outb = out + (size_t)tok0 * OUTD;

        // word: out[:, 1:301] — scalar coalesced both sides, unroll 4 for MLP
        // 19200 = 37*512 + 256
        #pragma unroll 4
        for (int k = 0; k < 37; ++k) {
            const int i = t2 + k * 512;
            const int t = i / WD;
            const int j = i - t * WD;
            outb[t * OUTD + 1 + j] = word_table[(size_t)input_word[tok0 + t] * WD + j];
        }
        if (t2 < 256) {
            const int i = t2 + 37 * 512;
            const int t = i / WD;
            const int j = i - t * WD;
            outb[t * OUTD + 1 + j] = word_table[(size_t)input_word[tok0 + t] * WD + j];
        }

        // pos: out[:, 401:501] — 6400 = 12*512 + 256
        #pragma unroll 4
        for (int k = 0; k < 12; ++k) {
            const int i = t2 + k * 512;
            const int t = i / PD;
            const int j = i - t * PD;
            outb[t * OUTD + 401 + j] = pos_table[input_pos[tok0 + t] * PD + j];
        }
        if (t2 < 256) {
            const int i = t2 + 12 * 512;
            const int t = i / PD;
            const int j = i - t * PD;
            outb[t * OUTD + 401 + j] = pos_table[input_pos[tok0 + t] * PD + j];
        }

        // privacy distance: out[:, 0]
        if (t2 < TPB) {
            const int j = (tok0 & (LS - 1)) + t2;
            const int wj = j >> 6, bj = j & 63;
            int last = -1000;
            {
                unsigned long long x = s_mask[wj] & ((2ull << bj) - 1ull);
                int w = wj;
                while (true) {
                    if (x) { last = w * 64 + 63 - __clzll(x); break; }
                    if (--w < 0) break;
                    x = s_mask[w];
                }
            }
            int nxt = 1000;
            {
                unsigned long long x = s_mask[wj] & (~0ull << bj);
                int w = wj;
                while (true) {
                    if (x) { nxt = w * 64 + (int)__ffsll((long long)x) - 1; break; }
                    if (++w >= LS / 64) break;
                    x = s_mask[w];
                }
            }
            outb[t2 * OUTD] = (float)min(j - last, nxt - j);
        }
    }
}

extern "C" void kernel_launch(void* const* d_in, const int* in_sizes, int n_in,
                              void* d_out, int out_size, void* d_ws, size_t ws_size,
                              hipStream_t stream) {
    const int*   input_word = (const int*)d_in[0];
    const int*   input_char = (const int*)d_in[1];
    const int*   input_pos  = (const int*)d_in[2];
    const float* word_table = (const float*)d_in[3];
    const float* char_table = (const float*)d_in[4];
    const float* pos_table  = (const float*)d_in[5];
    const float* conv_w     = (const float*)d_in[6];
    const float* conv_b     = (const float*)d_in[7];
    float* out = (float*)d_out;

    _Float16* P = (_Float16*)d_ws;                             // 76800 B

    precompute_P<<<dim3(NC, KK), 128, 0, stream>>>(conv_w, char_table, P);
    main_kernel<<<(BS * LS) / TPB, NTHR, 0, stream>>>(
        input_word, input_char, input_pos, word_table, pos_table, conv_b, P, out);
}

// Round 12
// 39.713 us; speedup vs baseline: 1.0465x; 1.0465x over previous
//
#include <hip/hip_runtime.h>
#include <hip/hip_fp16.h>

#define BS 64
#define LS 512
#define CL 32
#define WD 300
#define NC 100
#define CD 100
#define PD 100
#define NF 100
#define KK 3
#define OPAD 128                  // k-row padded to 128 f16 = 256 B = 8 full bank sweeps
#define PROW (KK*OPAD)            // 384 f16 = 768 B per char
#define PBYTES (NC*PROW*2)        // 76800 B
#define NV4 (PBYTES/16)           // 4800 uint4
#define OUTD 501
#define TPB 64                    // tokens per block
#define NTHR 1024
#define NCOPY 640                 // copy-role threads (10 waves)
#define NCHAR 384                 // char-role threads (6 waves)

typedef _Float16 h2 __attribute__((ext_vector_type(2)));

// ---------- Kernel 1: P[c][k][o] = sum_i conv_w[o,i,k] * char_table[c,i] (f16) ----------
__global__ void precompute_P(const float* __restrict__ conv_w,
                             const float* __restrict__ char_table,
                             _Float16* __restrict__ P) {
    const int c = blockIdx.x;      // 0..99
    const int k = blockIdx.y;      // 0..2
    const int o = threadIdx.x;     // 0..127
    __shared__ float row[CD];
    if (o < CD) row[o] = char_table[c * CD + o];
    __syncthreads();
    float acc = 0.f;
    if (o < NF) {
        const float* w = conv_w + o * (CD * KK) + k;
        #pragma unroll 4
        for (int i = 0; i < CD; ++i) acc += w[i * KK] * row[i];
    }
    P[(c * KK + k) * OPAD + o] = (_Float16)acc;    // o in [100,128) stores 0
}

// ---------- Kernel 2: fused, wave-specialized (6 char + 10 copy waves) ----------
// Pre-barrier: all waves stage P->LDS, ballot privacy masks, pack char ids.
// Post-barrier: waves 0-5 = char CNN (LDS pipe is per-CU: 6 waves saturate it)
// then pos copy + dist; waves 6-15 = word copy (the long HBM pole gets 25%
// more issue width). Both pipes busy concurrently, sides time-balanced.
__global__ __launch_bounds__(NTHR, 8) void main_kernel(
        const int* __restrict__ input_word,
        const int* __restrict__ input_char,
        const int* __restrict__ input_pos,
        const float* __restrict__ word_table,
        const float* __restrict__ pos_table,
        const float* __restrict__ conv_b,
        const _Float16* __restrict__ Pg,
        float* __restrict__ out) {
    __shared__ alignas(16) _Float16 Pl[NC * PROW];         // 76800 B
    __shared__ alignas(16) unsigned char s_char[TPB * CL]; // 2048 B packed char ids
    __shared__ unsigned long long s_mask[LS / 64];         // 64 B  (total 78912 B -> 2 blocks/CU)

    const int tid  = threadIdx.x;
    const int tok0 = blockIdx.x * TPB;

    // ---- 1. P staging loads into regs (all waves) ----
    const uint4* src = (const uint4*)Pg;
    const uint4 s0 = src[tid];
    const uint4 s1 = src[tid + NTHR];
    const uint4 s2 = src[tid + 2 * NTHR];
    const uint4 s3 = src[tid + 3 * NTHR];
    uint4 s4 = {};
    const bool h4 = tid < (NV4 - 4 * NTHR);   // tid < 704 (wave-uniform boundary)
    if (h4) s4 = src[tid + 4 * NTHR];

    // ---- 2. privacy-mask ballot (threads 0..511) ----
    if (tid < LS) {
        const int p = input_pos[(tok0 >> 9) * LS + tid];
        const bool pm = (p == 3) | (p == 7) | (p == 11);
        const unsigned long long b = __ballot(pm);
        if ((tid & 63) == 0) s_mask[tid >> 6] = b;
    }

    // ---- 3. char ids packed to bytes (512 dwords) ----
    if (tid < (TPB * CL) / 4) {
        const int4 c4 = ((const int4*)(input_char + tok0 * CL))[tid];
        ((unsigned*)s_char)[tid] =
            (unsigned)c4.x | ((unsigned)c4.y << 8) | ((unsigned)c4.z << 16) | ((unsigned)c4.w << 24);
    }

    // ---- 4. write staged P to LDS, barrier ----
    {
        uint4* dst = (uint4*)Pl;
        dst[tid] = s0;
        dst[tid + NTHR] = s1;
        dst[tid + 2 * NTHR] = s2;
        dst[tid + 3 * NTHR] = s3;
        if (h4) dst[tid + 4 * NTHR] = s4;
    }
    __syncthreads();

    if (tid < NCHAR) {
        // ================== CHAR ROLE: waves 0-5 ==================
        const int wid  = tid >> 6;
        const int lane = tid & 63;
        const int l    = lane & 15;          // filter octet (0..15)
        const char* Pb = (const char*)Pl + l * 16;
        const unsigned* s_cw = (const unsigned*)s_char;

        #pragma unroll 1
        for (int pass = 0; pass < 3; ++pass) {
            const int slot = wid * 3 + pass;             // 0..17, wave-uniform
            if (slot < 16) {
                const int tb = slot * 4 + (lane >> 4);   // token in block
                h2 a0[4], a1[4], m[4];
                #pragma unroll
                for (int i = 0; i < 4; ++i) {
                    a0[i] = (h2)(_Float16)0;
                    a1[i] = (h2)(_Float16)0;
                    m[i]  = (h2)(_Float16)(-60000.f);
                }
                #pragma unroll 2
                for (int w = 0; w < CL / 4; ++w) {
                    const unsigned wd = s_cw[tb * (CL / 4) + w];   // 4 packed char ids
                    #pragma unroll
                    for (int b = 0; b < 4; ++b) {
                        const int ca = (int)((wd >> (8 * b)) & 0xFFu) * (PROW * 2);
                        const uint4 r0 = *(const uint4*)(Pb + ca + 0 * (OPAD * 2));
                        const uint4 r1 = *(const uint4*)(Pb + ca + 1 * (OPAD * 2));
                        const uint4 r2 = *(const uint4*)(Pb + ca + 2 * (OPAD * 2));
                        #pragma unroll
                        for (int i = 0; i < 4; ++i) {
                            const unsigned c0 = (i == 0) ? r0.x : (i == 1) ? r0.y : (i == 2) ? r0.z : r0.w;
                            const unsigned c1 = (i == 0) ? r1.x : (i == 1) ? r1.y : (i == 2) ? r1.z : r1.w;
                            const unsigned c2 = (i == 0) ? r2.x : (i == 1) ? r2.y : (i == 2) ? r2.z : r2.w;
                            const h2 p0 = __builtin_bit_cast(h2, c0);
                            const h2 p1 = __builtin_bit_cast(h2, c1);
                            const h2 p2 = __builtin_bit_cast(h2, c2);
                            const h2 y = a0[i] + p2;               // y[t]
                            m[i]  = __builtin_elementwise_max(m[i], y);
                            a0[i] = a1[i] + p1;
                            a1[i] = p0;
                        }
                    }
                }
                // tail: y[32] = a0, y[33] = a1; write cols 301..400
                if (l < 13) {
                    float mm[8];
                    #pragma unroll
                    for (int i = 0; i < 4; ++i) {
                        const h2 v = __builtin_elementwise_max(m[i], __builtin_elementwise_max(a0[i], a1[i]));
                        mm[2 * i]     = (float)v.x;
                        mm[2 * i + 1] = (float)v.y;
                    }
                    const float4 b0 = *(const float4*)(conv_b + 8 * l);
                    float* outc = out + (size_t)(tok0 + tb) * OUTD + 301 + 8 * l;
                    outc[0] = tanhf(mm[0] + b0.x);
                    outc[1] = tanhf(mm[1] + b0.y);
                    outc[2] = tanhf(mm[2] + b0.z);
                    outc[3] = tanhf(mm[3] + b0.w);
                    if (l < 12) {
                        const float4 b1 = *(const float4*)(conv_b + 8 * l + 4);
                        outc[4] = tanhf(mm[4] + b1.x);
                        outc[5] = tanhf(mm[5] + b1.y);
                        outc[6] = tanhf(mm[6] + b1.z);
                        outc[7] = tanhf(mm[7] + b1.w);
                    }
                }
            }
        }

        // ---- pos copy on char waves: out[:, 401:501], float4 ----
        for (int i = tid; i < TPB * (PD / 4); i += NCHAR) {
            const int t = i / (PD / 4);
            const int j = i - t * (PD / 4);
            const int p = input_pos[tok0 + t];
            const float4 v = ((const float4*)pos_table)[p * (PD / 4) + j];
            float* o = out + (size_t)(tok0 + t) * OUTD + 401 + 4 * j;
            o[0] = v.x; o[1] = v.y; o[2] = v.z; o[3] = v.w;
        }

        // ---- privacy distance: out[:, 0] ----
        if (tid < TPB) {
            const int j = (tok0 & (LS - 1)) + tid;
            const int wj = j >> 6, bj = j & 63;
            int last = -1000;
            {
                unsigned long long x = s_mask[wj] & ((2ull << bj) - 1ull);
                int w = wj;
                while (true) {
                    if (x) { last = w * 64 + 63 - __clzll(x); break; }
                    if (--w < 0) break;
                    x = s_mask[w];
                }
            }
            int nxt = 1000;
            {
                unsigned long long x = s_mask[wj] & (~0ull << bj);
                int w = wj;
                while (true) {
                    if (x) { nxt = w * 64 + (int)__ffsll((long long)x) - 1; break; }
                    if (++w >= LS / 64) break;
                    x = s_mask[w];
                }
            }
            out[(size_t)(tok0 + tid) * OUTD] = (float)min(j - last, nxt - j);
        }
    } else {
        // ================== WORD-COPY ROLE: waves 6-15 (640 threads) ==================
        const int t2 = tid - NCHAR;

        // word: out[:, 1:301] — float4 gathers + coalesced 16B-stride stores
        #pragma unroll 2
        for (int i = t2; i < TPB * (WD / 4); i += NCOPY) {
            const int t = i / (WD / 4);
            const int j = i - t * (WD / 4);
            const int w = input_word[tok0 + t];
            const float4 v = ((const float4*)word_table)[(size_t)w * (WD / 4) + j];
            float* o = out + (size_t)(tok0 + t) * OUTD + 1 + 4 * j;
            o[0] = v.x; o[1] = v.y; o[2] = v.z; o[3] = v.w;
        }
    }
}

extern "C" void kernel_launch(void* const* d_in, const int* in_sizes, int n_in,
                              void* d_out, int out_size, void* d_ws, size_t ws_size,
                              hipStream_t stream) {
    const int*   input_word = (const int*)d_in[0];
    const int*   input_char = (const int*)d_in[1];
    const int*   input_pos  = (const int*)d_in[2];
    const float* word_table = (const float*)d_in[3];
    const float* char_table = (const float*)d_in[4];
    const float* pos_table  = (const float*)d_in[5];
    const float* conv_w     = (const float*)d_in[6];
    const float* conv_b     = (const float*)d_in[7];
    float* out = (float*)d_out;

    _Float16* P = (_Float16*)d_ws;                             // 76800 B

    precompute_P<<<dim3(NC, KK), 128, 0, stream>>>(conv_w, char_table, P);
    main_kernel<<<(BS * LS) / TPB, NTHR, 0, stream>>>(
        input_word, input_char, input_pos, word_table, pos_table, conv_b, P, out);
}